// Round 6
// baseline (805.686 us; speedup 1.0000x reference)
//
#include <hip/hip_runtime.h>
#include <hip/hip_bf16.h>
#include <math.h>

#define NPOS 81920   // 512*8*4*5
#define CDIM 256
#define SIGMA 1e-4f
#define LEAK 0.2f

typedef __hip_bfloat16 bf16;
typedef __bf16 bf16x8 __attribute__((ext_vector_type(8)));
typedef float f32x4 __attribute__((ext_vector_type(4)));

__device__ __forceinline__ float bf2f(unsigned short u) {
    return __uint_as_float(((unsigned)u) << 16);
}
__device__ __forceinline__ unsigned short f2bfu(float f) {
    bf16 h = __float2bfloat16(f);
    return *reinterpret_cast<unsigned short*>(&h);
}

// ---------------- encoder: h = tanh([x+sigma*noise, rand] @ W_enc) + pos_emb ----------------
__global__ void encode_kernel(const float* __restrict__ x, const float* __restrict__ noise,
                              const float* __restrict__ rnd, const float* __restrict__ We,
                              const float* __restrict__ pe, bf16* __restrict__ H) {
    int p = blockIdx.x;
    int c = threadIdx.x;
    float a = x[p] + SIGMA * noise[p];
    float b = rnd[p];
    float z = a * We[c] + b * We[CDIM + c];
    z = fminf(15.f, fmaxf(-15.f, z));
    float e = __expf(2.f * z);
    float th = 1.f - 2.f / (e + 1.f);   // tanh(z) via hw exp
    H[(size_t)p * CDIM + c] = __float2bfloat16(th + pe[(p % 160) * CDIM + c]);
}

// ---------------- bsum[l][c] = bo[l,0,c]+bo[l,1,c]+bo[l,2,c] ----------------
__global__ void bias3_kernel(const float* __restrict__ bo, float* __restrict__ bsum) {
    int l = blockIdx.x, c = threadIdx.x;
    bsum[l * CDIM + c] = bo[l * 768 + c] + bo[l * 768 + 256 + c] + bo[l * 768 + 512 + c];
}

// ---------------- weight packs ----------------
// WqkvT layout [l][a*768+n][k] (== [l][2304][256] B^T): n<256 -> Wq, else Wkv (k then v)
__global__ void pack_qkv_kernel(const float* __restrict__ Wq, const float* __restrict__ Wkv,
                                bf16* __restrict__ out) {
    int mat = blockIdx.x / 768;
    int n = blockIdx.x % 768;
    int k = threadIdx.x;
    float v = (n < 256) ? Wq[(size_t)mat * 65536 + (size_t)k * 256 + n]
                        : Wkv[(size_t)mat * 131072 + (size_t)k * 512 + (n - 256)];
    out[(size_t)blockIdx.x * 256 + k] = __float2bfloat16(v);
}
// WoT layout [l][n][a*256+ck] (== [l][256][768] B^T over stacked K): = Wo[l][a][ck][n]
__global__ void pack_wo_kernel(const float* __restrict__ Wo, bf16* __restrict__ out) {
    int l = blockIdx.x / 256;
    int n = blockIdx.x % 256;
    int ck = threadIdx.x;
    for (int a = 0; a < 3; a++)
        out[(size_t)(l * 256 + n) * 768 + a * 256 + ck] =
            __float2bfloat16(Wo[(((size_t)(l * 3 + a)) * 256 + ck) * 256 + n]);
}

// ---------------- GA attention phase (r0 math: 4 ch/lane, 2-shfl reduce) --------------------
// qkv in LDS: us[row*200 + hh*48 + part*16 + ch] for the current 4-head group.
// lane = sl*16 + hh*4 + c4: seq-slot sl, head-in-group hh, channel-quad c4.
template <int AXIS>
__device__ __forceinline__ void ga_attn(const unsigned short* __restrict__ us,
                                        bf16* __restrict__ O, int cell, int hg,
                                        int wave, int lane) {
    constexpr int T      = (AXIS == 0) ? 8 : (AXIS == 1) ? 4 : 5;
    constexpr int STRIDE = (AXIS == 0) ? 20 : (AXIS == 1) ? 5 : 1;
    constexpr int NS     = (AXIS == 0) ? 20 : (AXIS == 1) ? 40 : 32;
    int c4 = lane & 3, hh = (lane >> 2) & 3, sl = lane >> 4;
    for (int s0 = 0; s0 < NS; s0 += 32) {
        int s = s0 + wave * 4 + sl;
        if (s >= NS) break;             // wave-uniform (NS % 4 == 0, s spans 4 per wave)
        int base;
        if (AXIS == 0)      base = s;
        else if (AXIS == 1) base = (s / 5) * 20 + (s % 5);
        else                base = s * 5;

        float q[T][4], k[T][4], v[T][4];
#pragma unroll
        for (int t = 0; t < T; t++) {
            const unsigned short* ub = us + (base + t * STRIDE) * 200 + hh * 48 + c4 * 4;
            ushort4 qu = *(const ushort4*)(ub);
            ushort4 ku = *(const ushort4*)(ub + 16);
            ushort4 vu = *(const ushort4*)(ub + 32);
            q[t][0] = bf2f(qu.x); q[t][1] = bf2f(qu.y); q[t][2] = bf2f(qu.z); q[t][3] = bf2f(qu.w);
            k[t][0] = bf2f(ku.x); k[t][1] = bf2f(ku.y); k[t][2] = bf2f(ku.z); k[t][3] = bf2f(ku.w);
            v[t][0] = bf2f(vu.x); v[t][1] = bf2f(vu.y); v[t][2] = bf2f(vu.z); v[t][3] = bf2f(vu.w);
        }
#pragma unroll
        for (int t = 0; t < T; t++) {
            float sc[T];
#pragma unroll
            for (int s2 = 0; s2 < T; s2++) {
                float p = q[t][0] * k[s2][0] + q[t][1] * k[s2][1] + q[t][2] * k[s2][2]
                        + q[t][3] * k[s2][3];
                p += __shfl_xor(p, 1);
                p += __shfl_xor(p, 2);
                sc[s2] = p * 0.25f;  // * DH^-0.5
            }
            float mx = sc[0];
#pragma unroll
            for (int s2 = 1; s2 < T; s2++) mx = fmaxf(mx, sc[s2]);
            float sum = 0.f;
#pragma unroll
            for (int s2 = 0; s2 < T; s2++) { sc[s2] = __expf(sc[s2] - mx); sum += sc[s2]; }
            float inv = 1.f / sum;
            float o0 = 0.f, o1 = 0.f, o2 = 0.f, o3 = 0.f;
#pragma unroll
            for (int s2 = 0; s2 < T; s2++) {
                o0 += sc[s2] * v[s2][0]; o1 += sc[s2] * v[s2][1];
                o2 += sc[s2] * v[s2][2]; o3 += sc[s2] * v[s2][3];
            }
            ushort4 st;
            st.x = f2bfu(o0 * inv); st.y = f2bfu(o1 * inv);
            st.z = f2bfu(o2 * inv); st.w = f2bfu(o3 * inv);
            int row = base + t * STRIDE;
            *(ushort4*)((unsigned short*)O + (size_t)(cell * 160 + row) * 768 + AXIS * 256
                        + (hg * 4 + hh) * 16 + c4 * 4) = st;
        }
    }
}

// ================= GA kernel: fused QKV-GEMM + axial attention =================
// Block = one 160-row cell x one axis, 512 threads (8 waves, 2/SIMD), 1 block/CU (142.5 KB LDS;
// gfx950 allows 160 KB/workgroup — AITER's attn uses 160 KB).
// Fixes the measured r2/r3 failure modes:
//  - H-cell staged into LDS ONCE (r2 restaged 4x -> 184 MB FETCH; r3 read A from global -> 16x
//    L2 amplification, 522 MB FETCH).
//  - wave-pair per head: wave (hh=wave&3, mhalf=wave>>2) GEMMs M=80 rows of head hg*4+hh;
//    acc[5][3] = 60 regs.
//  - __launch_bounds__(512, 2) pins the allocator at <=256 VGPR/wave so the 8-wave block is
//    always launchable (r5 used (512,1): allocator could exceed 256 -> launch-out-of-resources).
//  - attention = r0's proven 4ch/lane 2-shfl form, reading qkv from LDS (kills the L3 wall
//    that bounded the standalone attn at 29 us/chunk vs its 4.7 us VALU floor).
// QKV never touches global memory. Only O is written.
__global__ __launch_bounds__(512, 2) void ga_kernel(
    const bf16* __restrict__ Hg, const bf16* __restrict__ Wqkv, bf16* __restrict__ Oa,
    int cells) {
    __shared__ __bf16 smem[72960];  // 80 KB H-cell + 62.5 KB (160x200 ushort) qkv
    int tid = threadIdx.x;
    int wave = tid >> 6, lane = tid & 63;
    int quad = lane >> 4, m = lane & 15;
    int cell = blockIdx.x % cells;
    int axis = blockIdx.x / cells;
    const bf16* Hc = Hg + (size_t)cell * 160 * CDIM;
    unsigned short* us = (unsigned short*)(smem + 40960);

    // stage H cell [160][256] once; LDS linear, global source pre-swizzled:
    // LDS[rd][sd*8..] = H[rd][(sd^((rd>>1)&7))*8..]  (r2-verified pattern)
#pragma unroll
    for (int rr = 0; rr < 10; rr++) {
        int rd = rr * 16 + (tid >> 5);
        int sd = tid & 31;
        int sl = sd ^ ((rd >> 1) & 7);
        __builtin_amdgcn_global_load_lds(
            (const __attribute__((address_space(1))) void*)(Hc + (size_t)rd * CDIM + sl * 8),
            (__attribute__((address_space(3))) void*)(smem + rd * 256 + sd * 8), 16, 0, 0);
    }

    int hh = wave & 3, mhalf = wave >> 2;
#pragma unroll 1
    for (int hg = 0; hg < 4; hg++) {
        __syncthreads();  // hg=0: stage drained; else: prev group's attn done reading us

        int h = hg * 4 + hh;            // this wave's head
        f32x4 acc[5][3] = {};
#pragma unroll
        for (int kk = 0; kk < 8; kk++) {
            bf16x8 bfrag[3], afr[5];
#pragma unroll
            for (int p = 0; p < 3; p++)
                bfrag[p] = *(const bf16x8*)(Wqkv +
                    (size_t)(axis * 768 + p * 256 + h * 16 + m) * 256 + kk * 32 + quad * 8);
#pragma unroll
            for (int mf = 0; mf < 5; mf++) {
                int row = mhalf * 80 + mf * 16 + m;
                afr[mf] = *(const bf16x8*)(smem + row * 256 +
                                           (((kk * 4 + quad) ^ ((row >> 1) & 7)) * 8));
            }
#pragma unroll
            for (int mf = 0; mf < 5; mf++)
#pragma unroll
                for (int p = 0; p < 3; p++)
                    acc[mf][p] = __builtin_amdgcn_mfma_f32_16x16x32_bf16(afr[mf], bfrag[p],
                                                                         acc[mf][p], 0, 0, 0);
        }

        // qkv -> LDS: us[row*200 + hh*48 + p*16 + m]
#pragma unroll
        for (int mf = 0; mf < 5; mf++)
#pragma unroll
            for (int p = 0; p < 3; p++)
#pragma unroll
                for (int r2 = 0; r2 < 4; r2++) {
                    int row = mhalf * 80 + mf * 16 + quad * 4 + r2;
                    us[row * 200 + hh * 48 + p * 16 + m] = f2bfu(acc[mf][p][r2]);
                }
        __syncthreads();

        if (axis == 0)      ga_attn<0>(us, Oa, cell, hg, wave, lane);
        else if (axis == 1) ga_attn<1>(us, Oa, cell, hg, wave, lane);
        else                ga_attn<2>(us, Oa, cell, hg, wave, lane);
    }
}

// ================= W kernel: Wo projection, 128x128 tile, BK=64, K=768 (r11 engine) =========
__global__ __launch_bounds__(256, 2) void wo_kernel(
    const bf16* __restrict__ Ow, const bf16* __restrict__ WoTl, bf16* __restrict__ Hnw,
    const float* __restrict__ bias) {
    __shared__ __bf16 smem[32768];  // 64 KB
    int tid = threadIdx.x;
    int wave = tid >> 6, lane = tid & 63;
    int quad = lane >> 4, m = lane & 15;
    __bf16* As = smem;              // [2][128*64]  (2 x 16 KB)
    __bf16* Bs = smem + 16384;      // [2][128*64]
    int bid = blockIdx.x;
    int xcd = bid & 7, slot = bid >> 3;
    int g = slot >> 1;
    int nb = slot & 1;              // 2 N-blocks of 128
    int mb = xcd + 8 * g;
    int bm = mb * 128, bn = nb * 128;
    int wr = (wave >> 1) * 64, wc = (wave & 1) * 64;
    f32x4 acc[4][4] = {};

#define STAGE_W(buf, k0)                                                                       \
    {                                                                                          \
        _Pragma("unroll") for (int rep = 0; rep < 4; rep++) {                                  \
            int ch = rep * 256 + wave * 64 + lane;                                             \
            int row = ch >> 3, cc = ch & 7, gc = cc ^ (row & 7);                               \
            __builtin_amdgcn_global_load_lds(                                                  \
                (const __attribute__((address_space(1))) void*)(Ow + (size_t)(bm + row) * 768  \
                                                                + (k0) + gc * 8),              \
                (__attribute__((address_space(3))) void*)(As + (buf) * 8192                    \
                                                          + (rep * 256 + wave * 64) * 8),      \
                16, 0, 0);                                                                     \
        }                                                                                      \
        _Pragma("unroll") for (int rep = 0; rep < 4; rep++) {                                  \
            int ch = rep * 256 + wave * 64 + lane;                                             \
            int row = ch >> 3, cc = ch & 7, gc = cc ^ (row & 7);                               \
            __builtin_amdgcn_global_load_lds(                                                  \
                (const __attribute__((address_space(1))) void*)(WoTl + (size_t)(bn + row) * 768\
                                                                + (k0) + gc * 8),              \
                (__attribute__((address_space(3))) void*)(Bs + (buf) * 8192                    \
                                                          + (rep * 256 + wave * 64) * 8),      \
                16, 0, 0);                                                                     \
        }                                                                                      \
    }

    STAGE_W(0, 0);
#pragma unroll
    for (int it = 0; it < 12; it++) {
        __syncthreads();
        if (it < 11) STAGE_W((it + 1) & 1, (it + 1) * 64);
        const __bf16* Ab = As + (it & 1) * 8192;
        const __bf16* Bb = Bs + (it & 1) * 8192;
#pragma unroll
        for (int kk = 0; kk < 2; kk++) {
            bf16x8 af[4], bfr[4];
#pragma unroll
            for (int i = 0; i < 4; i++) {
                int r = wr + i * 16 + m, cix = kk * 4 + quad;
                af[i] = *(const bf16x8*)(Ab + r * 64 + ((cix ^ (r & 7)) * 8));
            }
#pragma unroll
            for (int j = 0; j < 4; j++) {
                int r = wc + j * 16 + m, cix = kk * 4 + quad;
                bfr[j] = *(const bf16x8*)(Bb + r * 64 + ((cix ^ (r & 7)) * 8));
            }
#pragma unroll
            for (int i = 0; i < 4; i++)
#pragma unroll
                for (int j = 0; j < 4; j++)
                    acc[i][j] = __builtin_amdgcn_mfma_f32_16x16x32_bf16(af[i], bfr[j], acc[i][j], 0, 0, 0);
        }
    }
#undef STAGE_W

#pragma unroll
    for (int i = 0; i < 4; i++)
#pragma unroll
        for (int j = 0; j < 4; j++)
#pragma unroll
            for (int r = 0; r < 4; r++) {
                int row = bm + wr + i * 16 + quad * 4 + r;
                int col = bn + wc + j * 16 + m;
                float v = acc[i][j][r] + bias[col];
                v = v >= 0.f ? v : LEAK * v;
                Hnw[(size_t)row * CDIM + col] = __float2bfloat16(v);
            }
}

// ---------------- decoder: out = sigmoid(H @ Wd + bd) ----------------
__global__ void decode_kernel(const bf16* __restrict__ H, const float* __restrict__ Wd,
                              const float* __restrict__ bd, float* __restrict__ out) {
    int tid = threadIdx.x;
    int pos = blockIdx.x * 4 + (tid >> 6);
    int lane = tid & 63;
    float acc = 0.f;
#pragma unroll
    for (int q = 0; q < 4; q++) {
        int c = lane + q * 64;
        acc += __bfloat162float(H[(size_t)pos * CDIM + c]) * Wd[c];
    }
#pragma unroll
    for (int off = 32; off > 0; off >>= 1) acc += __shfl_down(acc, off);
    if (lane == 0) out[pos] = 1.f / (1.f + __expf(-(acc + bd[0])));
}

extern "C" void kernel_launch(void* const* d_in, const int* in_sizes, int n_in,
                              void* d_out, int out_size, void* d_ws, size_t ws_size,
                              hipStream_t stream) {
    const float* x     = (const float*)d_in[0];
    const float* noise = (const float*)d_in[1];
    const float* rnd   = (const float*)d_in[2];
    const float* We    = (const float*)d_in[3];
    const float* pe    = (const float*)d_in[4];
    const float* Wq    = (const float*)d_in[5];
    const float* Wkv   = (const float*)d_in[6];
    const float* Wo    = (const float*)d_in[7];
    const float* bo    = (const float*)d_in[8];
    const float* Wd    = (const float*)d_in[9];
    const float* bd    = (const float*)d_in[10];
    float* out = (float*)d_out;

    // ws: H0 | H1 | WqkvT | WoT | bsum | O (single buffer; QKV eliminated by GA fusion)
    bf16* H0    = (bf16*)d_ws;
    bf16* H1    = H0 + (size_t)NPOS * CDIM;
    bf16* WqkvT = H1 + (size_t)NPOS * CDIM;
    bf16* WoT   = WqkvT + (size_t)2 * 2304 * 256;
    float* bsum = (float*)(WoT + (size_t)2 * 256 * 768);
    bf16* O     = (bf16*)(bsum + 512);

    size_t fixed = ((size_t)2 * NPOS * CDIM + (size_t)2 * 2304 * 256 + (size_t)2 * 256 * 768) * 2
                   + 512 * 4;
    // mc must be a multiple of 160 (cells) and 1024 (W-engine XCD swizzle: nMblk % 8 == 0).
    // c=1 -> O = 126 MB, total ~214 MB (same footprint class as the passing r0 layout).
    int c = 1;
    while (c < 64 && fixed + (size_t)(NPOS / c) * 768 * 2 > ws_size) c <<= 1;
    int mc = NPOS / c;
    bf16* Hbuf[3] = { H0, H1, H0 };  // layer l: GA reads Hbuf[l], W writes Hbuf[l+1]

    pack_qkv_kernel<<<6 * 768, 256, 0, stream>>>(Wq, Wkv, WqkvT);
    pack_wo_kernel<<<2 * 256, 256, 0, stream>>>(Wo, WoT);
    bias3_kernel<<<2, 256, 0, stream>>>(bo, bsum);
    encode_kernel<<<NPOS, 256, 0, stream>>>(x, noise, rnd, We, pe, H0);

    int nMblk = mc / 128;
    int cells = mc / 160;

    // chunk t: GA computes O(t) = attn(H(t)@Wqkv) fused; W computes Hnext(t) = O(t)@WoT.
    // W(t) directly follows GA(t) -> single O buffer, no pipeline, no ping-pong.
    for (int t = 0; t < 2 * c; t++) {
        int lg = t / c, cg = t % c;
        ga_kernel<<<cells * 3, 512, 0, stream>>>(
            Hbuf[lg] + (size_t)cg * mc * CDIM, WqkvT + (size_t)lg * 2304 * 256, O, cells);
        wo_kernel<<<nMblk * 2, 256, 0, stream>>>(
            O, WoT + (size_t)lg * 256 * 768, Hbuf[lg + 1] + (size_t)cg * mc * CDIM,
            bsum + lg * CDIM);
    }

    decode_kernel<<<NPOS / 4, 256, 0, stream>>>(Hbuf[2], Wd, bd, out);
}